// Round 14
// baseline (1263.642 us; speedup 1.0000x reference)
//
#include <hip/hip_runtime.h>
#include <hip/hip_bf16.h>
#include <stdint.h>

// ---------------------------------------------------------------------------
// SpMiddle conv stack — fp16 MFMA implicit-GEMM, v5.
// vs v4 (measured LDS-read-bound, MfmaUtil 26%): 32x32x16 MFMA, wave = 64x64
// (mt2 x nf2, no N-split dup of A-reads), 128-thread blocks, per-(kd,kh)
// staging (16.6KB LDS, ~9 blk/CU). LDS bytes/output halved, MFMA/read 2x.
// ---------------------------------------------------------------------------

typedef _Float16 h8 __attribute__((ext_vector_type(8)));
typedef float f16v __attribute__((ext_vector_type(16)));

#define HCONST 128
#define WCONST 128

// ---- scatter: last-write-wins via owner = atomicMax(point index) ----------
__global__ void scatter_owner_kernel(const int* __restrict__ coords,
                                     int* __restrict__ owner,
                                     unsigned char* __restrict__ mask0, int N) {
    int n = blockIdx.x * blockDim.x + threadIdx.x;
    if (n >= N) return;
    int z = coords[n * 4 + 1];
    int y = coords[n * 4 + 2];
    int x = coords[n * 4 + 3];
    int pos = (z * HCONST + y) * WCONST + x;
    atomicMax(&owner[pos], n);
    mask0[pos] = 1;
}

// grid has 32 channels (ci 16..31 stay zero from memset); fp16
__global__ void scatter_write_kernel(const float* __restrict__ feats,
                                     const int* __restrict__ coords,
                                     const int* __restrict__ owner,
                                     _Float16* __restrict__ grid, int N) {
    int n = blockIdx.x * blockDim.x + threadIdx.x;
    if (n >= N) return;
    int z = coords[n * 4 + 1];
    int y = coords[n * 4 + 2];
    int x = coords[n * 4 + 3];
    int pos = (z * HCONST + y) * WCONST + x;
    if (owner[pos] != n) return;  // last write wins
    _Float16* d = grid + (size_t)pos * 32;
#pragma unroll
    for (int c = 0; c < 16; ++c) d[c] = (_Float16)feats[(size_t)n * 16 + c];
}

// ---- occupancy mask: OR over conv window -----------------------------------
template <int KD, int KHW, int SD, int PD, int PHW>
__global__ void occupancy_kernel(const unsigned char* __restrict__ min_,
                                 unsigned char* __restrict__ mout,
                                 int Din, int Dout) {
    int idx = blockIdx.x * blockDim.x + threadIdx.x;
    int total = Dout * HCONST * WCONST;
    if (idx >= total) return;
    int ow = idx % WCONST;
    int oh = (idx / WCONST) % HCONST;
    int od = idx / (WCONST * HCONST);
    unsigned char r = 0;
    for (int kd = 0; kd < KD; ++kd) {
        int d = od * SD - PD + kd;
        if (d < 0 || d >= Din) continue;
        for (int kh = 0; kh < KHW; ++kh) {
            int h = oh - PHW + kh;
            if ((unsigned)h >= (unsigned)HCONST) continue;
            for (int kw = 0; kw < KHW; ++kw) {
                int w = ow - PHW + kw;
                if ((unsigned)w >= (unsigned)WCONST) continue;
                r |= min_[(d * HCONST + h) * WCONST + w];
            }
        }
    }
    mout[idx] = r ? 1 : 0;
}

// ---- weight prep: fp32 [k][ci][co] -> fp16 [k][ks16][half][co][8] ----------
// 32x32x16 B-frag native: lane l loads co=(l&31)+nf*32, k=ks*16+(l>>5)*8+j;
// a wave's 64 loads are 1KB contiguous.
__global__ void prep_w_kernel(const float* __restrict__ src, _Float16* __restrict__ dst,
                              int K3, int CIN, int CINP, int COUT) {
    int idx = blockIdx.x * blockDim.x + threadIdx.x;
    int total = K3 * CINP * COUT;
    if (idx >= total) return;
    int j  = idx & 7;
    int t  = idx >> 3;
    int co = t % COUT; t /= COUT;
    int half = t & 1;  t >>= 1;
    int KSP = CINP / 16;
    int ks = t % KSP;
    int k  = t / KSP;
    int ci = ks * 16 + half * 8 + j;
    float v = (ci < CIN) ? src[((size_t)k * CIN + ci) * COUT + co] : 0.f;
    dst[idx] = (_Float16)v;
}

// ---- conv + BN + ReLU + mask, fp16 32x32x16 MFMA implicit GEMM -------------
// Block = one (oh, od): M = 128 w, N = COUT. 2 waves, M-split (64 rows each).
// Per wave: mt=2 (32-row frags) x nf=COUT/32 (32-col frags).
// Per (kd,kh): stage one input row (WIN x CIN) into XOR-swizzled LDS, then
// KW x KS x (2 A-reads + NFRAG B-loads + 2*NFRAG MFMA).
template <int CIN, int COUT, int KD, int KHW, int SD, int PD, int PHW, bool OUT_F32>
__global__ __launch_bounds__(128) void conv_mfma_kernel(
    const _Float16* __restrict__ X, const _Float16* __restrict__ Wt,
    const float* __restrict__ scale, const float* __restrict__ bias,
    const unsigned char* __restrict__ mask, void* __restrict__ outv,
    int Din) {
    constexpr int KW = KHW, KH = KHW;
    constexpr int KS = CIN / 16;            // 16-wide k-slices per kw
    constexpr int NFRAG = COUT / 32;        // 1 or 2
    constexpr int PWOFF = (KHW == 3) ? 1 : 0;
    constexpr int WIN = 128 + 2 * PWOFF;    // staged w extent (130|128)
    constexpr int CINB = CIN * 2;           // row bytes (pow2 -> XOR swizzle)
    constexpr int CPR = CIN / 8;            // 16B chunks per row
    constexpr int CHUNKS = WIN * CPR;       // staged per (kd,kh)
    constexpr int NIT = (CHUNKS + 127) / 128;

    __shared__ char lds[WIN * CINB];

    const int tid = threadIdx.x;
    const int lane = tid & 63, wm = tid >> 6;   // 2 waves: M rows wm*64..+64
    const int lr = lane & 31, lh = lane >> 5;   // frag row/col, k-half
    const int oh = blockIdx.x, od = blockIdx.y;

    f16v acc[2][NFRAG];
#pragma unroll
    for (int mt = 0; mt < 2; ++mt)
#pragma unroll
        for (int nf = 0; nf < NFRAG; ++nf)
#pragma unroll
            for (int e = 0; e < 16; ++e) acc[mt][nf][e] = 0.f;

    for (int kd = 0; kd < KD; ++kd) {
        int din = od * SD - PD + kd;
        if (din < 0 || din >= Din) continue;          // block-uniform
#pragma unroll
        for (int kh = 0; kh < KH; ++kh) {
            int hin = oh - PHW + kh;
            if ((unsigned)hin >= 128u) continue;      // block-uniform
            __syncthreads();                          // protect prev LDS reads
            // ---- stage one input row (WIN x CIN), zero-fill OOB w ----
            const _Float16* src = X + (((size_t)din * 128 + hin) * 128) * CIN;
#pragma unroll
            for (int it = 0; it < NIT; ++it) {
                int c = tid + it * 128;
                if (c < CHUNKS) {
                    int r  = c / CPR;
                    int cq = c % CPR;
                    int w  = r - PWOFF;
                    uint4 v = {0u, 0u, 0u, 0u};
                    if ((unsigned)w < 128u)
                        v = *(const uint4*)(src + (size_t)w * CIN + cq * 8);
                    int byte = r * CINB + ((cq * 16) ^ ((r & (CPR - 1)) << 4));
                    *(uint4*)(lds + byte) = v;
                }
            }
            __syncthreads();
            // ---- compute: KW x KS phases ----
            const _Float16* wb = Wt + (size_t)(kd * KH + kh) * KW * KS * 2 * COUT * 8;
#pragma unroll
            for (int kw = 0; kw < KW; ++kw) {
                // B fragments for this kw: [ks][nf], 1KB-contiguous per load
                h8 Bf[KS][NFRAG];
#pragma unroll
                for (int ks = 0; ks < KS; ++ks)
#pragma unroll
                    for (int nf = 0; nf < NFRAG; ++nf) {
                        int co = nf * 32 + lr;
                        Bf[ks][nf] = *(const h8*)(
                            wb + (((size_t)(kw * KS + ks) * 2 + lh) * COUT + co) * 8);
                    }
#pragma unroll
                for (int ks = 0; ks < KS; ++ks) {
                    h8 Af[2];
#pragma unroll
                    for (int mt = 0; mt < 2; ++mt) {
                        int row = wm * 64 + mt * 32 + lr + kw;
                        int byte = row * CINB +
                                   ((ks * 32 + lh * 16) ^ ((row & (CPR - 1)) << 4));
                        Af[mt] = *(const h8*)(lds + byte);
                    }
#pragma unroll
                    for (int mt = 0; mt < 2; ++mt)
#pragma unroll
                        for (int nf = 0; nf < NFRAG; ++nf)
                            acc[mt][nf] = __builtin_amdgcn_mfma_f32_32x32x16_f16(
                                Af[mt], Bf[ks][nf], acc[mt][nf], 0, 0, 0);
                }
            }
        }
    }

    // epilogue: y = max(acc*s + b, 0) * mask
    // C layout (m74/m101): col = lane&31, row = (reg&3) + 8*(reg>>2) + 4*(lane>>5)
    const unsigned char* mrow = mask + ((size_t)od * 128 + oh) * 128;
    size_t obase = (((size_t)od * 128 + oh) * 128) * COUT;
#pragma unroll
    for (int nf = 0; nf < NFRAG; ++nf) {
        int co = nf * 32 + lr;
        float s = scale[co];
        float b = bias[co];
#pragma unroll
        for (int mt = 0; mt < 2; ++mt) {
#pragma unroll
            for (int r = 0; r < 16; ++r) {
                int wrow = (r & 3) + 8 * (r >> 2) + 4 * lh;
                int w = wm * 64 + mt * 32 + wrow;
                float y = fmaxf(acc[mt][nf][r] * s + b, 0.f);
                y = mrow[w] ? y : 0.f;
                if (OUT_F32)
                    ((float*)outv)[obase + (size_t)w * COUT + co] = y;
                else
                    ((_Float16*)outv)[obase + (size_t)w * COUT + co] = (_Float16)y;
            }
        }
    }
}

// ---------------------------------------------------------------------------
extern "C" void kernel_launch(void* const* d_in, const int* in_sizes, int n_in,
                              void* d_out, int out_size, void* d_ws, size_t ws_size,
                              hipStream_t stream) {
    const float* feats  = (const float*)d_in[0];
    const int*   coords = (const int*)d_in[1];
    const float* W_[11]; const float* S_[11]; const float* B_[11];
    for (int i = 0; i < 11; ++i) {
        W_[i] = (const float*)d_in[2 + 3 * i];
        S_[i] = (const float*)d_in[3 + 3 * i];
        B_[i] = (const float*)d_in[4 + 3 * i];
    }
    const int N = in_sizes[0] / 16;

    char* ws = (char*)d_ws;
    size_t off = 0;
    auto alloc = [&](size_t bytes) {
        void* p = ws + off;
        off = (off + bytes + 255) & ~(size_t)255;
        return p;
    };
    // fp16 ping-pong activation buffers (max layer: 344064*64 halves = 44 MB)
    const size_t BUF_BYTES = (size_t)22020096 * 2;
    _Float16* buf0 = (_Float16*)alloc(BUF_BYTES);
    _Float16* buf1 = (_Float16*)alloc(BUF_BYTES);
    unsigned char* m0 = (unsigned char*)alloc(671744);
    unsigned char* m1 = (unsigned char*)alloc(344064);
    unsigned char* m2 = (unsigned char*)alloc(163840);
    unsigned char* m3 = (unsigned char*)alloc(65536);
    int* owner = (int*)alloc((size_t)671744 * 4);
    // repacked fp16 weights (element counts: K3 * COUT * CINP)
    static const int WT_SZ[11] = {27*32*32, 27*32*32, 27*64*32,
                                  27*64*64, 27*64*64, 27*64*64, 27*64*64,
                                  27*64*64, 27*64*64, 27*64*64, 3*64*64};
    _Float16* Wt[11];
    for (int i = 0; i < 11; ++i) Wt[i] = (_Float16*)alloc((size_t)WT_SZ[i] * 2);
    (void)ws_size; (void)n_in; (void)out_size;

    _Float16* grid0 = buf1;  // (41,128,128,32) fp16 aliased into buf1
    const size_t GRID_BYTES = (size_t)671744 * 32 * 2;

    hipMemsetAsync(grid0, 0, GRID_BYTES, stream);
    hipMemsetAsync(m0, 0, 671744, stream);
    hipMemsetAsync(owner, 0xFF, (size_t)671744 * 4, stream);

    scatter_owner_kernel<<<(N + 255) / 256, 256, 0, stream>>>(coords, owner, m0, N);
    scatter_write_kernel<<<(N + 255) / 256, 256, 0, stream>>>(feats, coords, owner, grid0, N);

    occupancy_kernel<3, 3, 2, 1, 1><<<(21 * 128 * 128 + 255) / 256, 256, 0, stream>>>(m0, m1, 41, 21);
    occupancy_kernel<3, 3, 2, 0, 1><<<(10 * 128 * 128 + 255) / 256, 256, 0, stream>>>(m1, m2, 21, 10);
    occupancy_kernel<3, 1, 2, 0, 0><<<(4 * 128 * 128 + 255) / 256, 256, 0, stream>>>(m2, m3, 10, 4);

    // weight prep (w0 padded ci 16->32); layout [k][ks16][half][co][8]
    {
        static const int K3[11]   = {27,27,27,27,27,27,27,27,27,27,3};
        static const int CI[11]   = {16,32,32,64,64,64,64,64,64,64,64};
        static const int CIP[11]  = {32,32,32,64,64,64,64,64,64,64,64};
        static const int CO[11]   = {32,32,64,64,64,64,64,64,64,64,64};
        for (int i = 0; i < 11; ++i) {
            int total = K3[i] * CO[i] * CIP[i];
            prep_w_kernel<<<(total + 255) / 256, 256, 0, stream>>>(W_[i], Wt[i], K3[i], CI[i], CIP[i], CO[i]);
        }
    }

    // conv stack (blockIdx = {oh, od}, 128 threads)
    conv_mfma_kernel<32, 32, 3, 3, 1, 1, 1, false><<<dim3(128, 41), 128, 0, stream>>>(
        grid0, Wt[0], S_[0], B_[0], m0, buf0, 41);
    conv_mfma_kernel<32, 32, 3, 3, 1, 1, 1, false><<<dim3(128, 41), 128, 0, stream>>>(
        buf0, Wt[1], S_[1], B_[1], m0, buf1, 41);
    conv_mfma_kernel<32, 64, 3, 3, 2, 1, 1, false><<<dim3(128, 21), 128, 0, stream>>>(
        buf1, Wt[2], S_[2], B_[2], m1, buf0, 41);
    conv_mfma_kernel<64, 64, 3, 3, 1, 1, 1, false><<<dim3(128, 21), 128, 0, stream>>>(
        buf0, Wt[3], S_[3], B_[3], m1, buf1, 21);
    conv_mfma_kernel<64, 64, 3, 3, 1, 1, 1, false><<<dim3(128, 21), 128, 0, stream>>>(
        buf1, Wt[4], S_[4], B_[4], m1, buf0, 21);
    conv_mfma_kernel<64, 64, 3, 3, 1, 1, 1, false><<<dim3(128, 21), 128, 0, stream>>>(
        buf0, Wt[5], S_[5], B_[5], m1, buf1, 21);
    conv_mfma_kernel<64, 64, 3, 3, 2, 0, 1, false><<<dim3(128, 10), 128, 0, stream>>>(
        buf1, Wt[6], S_[6], B_[6], m2, buf0, 21);
    conv_mfma_kernel<64, 64, 3, 3, 1, 1, 1, false><<<dim3(128, 10), 128, 0, stream>>>(
        buf0, Wt[7], S_[7], B_[7], m2, buf1, 10);
    conv_mfma_kernel<64, 64, 3, 3, 1, 1, 1, false><<<dim3(128, 10), 128, 0, stream>>>(
        buf1, Wt[8], S_[8], B_[8], m2, buf0, 10);
    conv_mfma_kernel<64, 64, 3, 3, 1, 1, 1, false><<<dim3(128, 10), 128, 0, stream>>>(
        buf0, Wt[9], S_[9], B_[9], m2, buf1, 10);
    conv_mfma_kernel<64, 64, 3, 1, 2, 0, 0, true><<<dim3(128, 4), 128, 0, stream>>>(
        buf1, Wt[10], S_[10], B_[10], m3, (float*)d_out, 10);
}